// Round 1
// baseline (6909.882 us; speedup 1.0000x reference)
//
#include <hip/hip_runtime.h>
#include <cstdint>
#include <cstddef>

#define S_LEN 512
#define NB    64
#define NI    1024
#define NH    1024
#define NR    4096   // 4 gates * NH, interleaved r = j*4 + g  (g: 0=i,1=f,2=c,3=o)

typedef short bf16x8 __attribute__((ext_vector_type(8)));
typedef float f32x4  __attribute__((ext_vector_type(4)));

__device__ __forceinline__ short f2bf(float f) {
  uint32_t u = __float_as_uint(f);
  u += 0x7fff + ((u >> 16) & 1);          // RNE
  return (short)(u >> 16);
}
__device__ __forceinline__ float bf2f(short s) {
  return __uint_as_float(((uint32_t)(uint16_t)s) << 16);
}
__device__ __forceinline__ void gload16(const void* g, void* l) {
  __builtin_amdgcn_global_load_lds((const __attribute__((address_space(1))) void*)g,
                                   (__attribute__((address_space(3))) void*)l, 16, 0, 0);
}
__device__ __forceinline__ float sigm(float x) { return 1.0f / (1.0f + __expf(-x)); }

// ---------------- prep kernels ----------------

__global__ __launch_bounds__(256) void k_convert_x(const float* __restrict__ x,
                                                   short* __restrict__ xbf) {
  int tid = blockIdx.x * 256 + threadIdx.x;        // exactly SB*NI/4 threads
  float4 v = ((const float4*)x)[tid];
  short4 o;
  o.x = f2bf(v.x); o.y = f2bf(v.y); o.z = f2bf(v.z); o.w = f2bf(v.w);
  ((short4*)xbf)[tid] = o;
}

struct WPtrs { const float *xi, *xf, *xc, *xo, *hi, *hf, *hc, *ho; };

__global__ __launch_bounds__(256) void k_pack_w(WPtrs w, short* __restrict__ wxcat,
                                                short* __restrict__ whcat) {
  int tid  = blockIdx.x * 256 + threadIdx.x;       // NR*NI/4 threads
  int flat = tid * 4;
  int r = flat >> 10, k = flat & 1023;
  int j = r >> 2, g = r & 3;
  const float* px = (g == 0) ? w.xi : (g == 1) ? w.xf : (g == 2) ? w.xc : w.xo;
  const float* ph = (g == 0) ? w.hi : (g == 1) ? w.hf : (g == 2) ? w.hc : w.ho;
  float4 vx = *(const float4*)(px + j * 1024 + k);
  float4 vh = *(const float4*)(ph + j * 1024 + k);
  short4 ox, oh;
  ox.x = f2bf(vx.x); ox.y = f2bf(vx.y); ox.z = f2bf(vx.z); ox.w = f2bf(vx.w);
  oh.x = f2bf(vh.x); oh.y = f2bf(vh.y); oh.z = f2bf(vh.z); oh.w = f2bf(vh.w);
  *(short4*)(wxcat + flat) = ox;
  *(short4*)(whcat + flat) = oh;
}

struct BPtrs { const float *xi,*hi,*i_, *xf,*hf,*f_, *xc,*hc,*c_, *xo,*ho,*o_; };

__global__ __launch_bounds__(256) void k_init(BPtrs p, float* __restrict__ bias,
                                              short* __restrict__ h0, short* __restrict__ h1,
                                              float* __restrict__ c) {
  int tid = blockIdx.x * 256 + threadIdx.x;        // NB*NH threads
  c[tid]  = 0.0f;
  h0[tid] = 0;
  h1[tid] = 0;
  if (tid < NR) {
    int j = tid >> 2, g = tid & 3;
    const float* bx = (g == 0) ? p.xi : (g == 1) ? p.xf : (g == 2) ? p.xc : p.xo;
    const float* bh = (g == 0) ? p.hi : (g == 1) ? p.hf : (g == 2) ? p.hc : p.ho;
    const float* bb = (g == 0) ? p.i_ : (g == 1) ? p.f_ : (g == 2) ? p.c_ : p.o_;
    bias[tid] = bx[j] + bh[j] + bb[j];
  }
}

// ---------------- phase 1: gx = x @ Wx^T + bias  (bf16 MFMA, m97-style 128x128) --------------

__global__ __launch_bounds__(256) void gemm_x(const short* __restrict__ xbf,  // [32768][1024]
                                              const short* __restrict__ wx,   // [4096][1024]
                                              const float* __restrict__ bias, // [4096]
                                              short* __restrict__ gx) {       // [32768][4096]
  __shared__ __align__(16) short As[2][4096];   // [128][32] bf16, 64B rows
  __shared__ __align__(16) short Bs[2][4096];

  const int tid = threadIdx.x, wave = tid >> 6, lane = tid & 63;
  const int m0 = blockIdx.x * 128, n0 = blockIdx.y * 128;
  const char* aB = (const char*)xbf + (size_t)m0 * 2048;
  const char* bB = (const char*)wx + (size_t)n0 * 2048;

  f32x4 acc[4][4] = {};

  auto stage = [&](int kt, int buf) {
#pragma unroll
    for (int s2 = 0; s2 < 2; ++s2) {
      int seg = wave * 2 + s2;
      int L   = seg * 1024 + lane * 16;
      int row = L >> 6;           // 64-B rows
      int cb  = L & 63;
      gload16(aB + (size_t)row * 2048 + kt * 64 + cb, (char*)&As[buf][0] + L);
      gload16(bB + (size_t)row * 2048 + kt * 64 + cb, (char*)&Bs[buf][0] + L);
    }
  };

  const int wm = wave >> 1, wn = wave & 1;
  auto compute = [&](int buf) {
    const char* Ab = (const char*)&As[buf][0];
    const char* Bb = (const char*)&Bs[buf][0];
    bf16x8 a[4], b[4];
#pragma unroll
    for (int f = 0; f < 4; ++f) {
      int ar = wm * 64 + f * 16 + (lane & 15);
      a[f] = *(const bf16x8*)(Ab + ar * 64 + (lane >> 4) * 16);
      int br = wn * 64 + f * 16 + (lane & 15);
      b[f] = *(const bf16x8*)(Bb + br * 64 + (lane >> 4) * 16);
    }
#pragma unroll
    for (int i = 0; i < 4; ++i)
#pragma unroll
      for (int j = 0; j < 4; ++j)
        acc[i][j] = __builtin_amdgcn_mfma_f32_16x16x32_bf16(a[i], b[j], acc[i][j], 0, 0, 0);
  };

  stage(0, 0);
  __syncthreads();
  int buf = 0;
  for (int kt = 0; kt < 32; ++kt) {
    if (kt < 31) stage(kt + 1, buf ^ 1);
    compute(buf);
    __syncthreads();
    buf ^= 1;
  }

  const int colL = lane & 15;
#pragma unroll
  for (int j = 0; j < 4; ++j) {
    int   n  = n0 + wn * 64 + j * 16 + colL;
    float bv = bias[n];
#pragma unroll
    for (int i = 0; i < 4; ++i) {
#pragma unroll
      for (int q = 0; q < 4; ++q) {
        int m = m0 + wm * 64 + i * 16 + (lane >> 4) * 4 + q;
        gx[(size_t)m * NR + n] = f2bf(acc[i][j][q] + bv);
      }
    }
  }
}

// ---------------- per-step fused kernel ----------------
// WG w owns weight rows r in [w*32, w*32+32)  == hidden units j in [w*8, w*8+8), all 4 gates.
// pre[b][r] = gx[t][b][r] + sum_k h[b][k] * Wh[r][k]; then pointwise LSTM update.

__global__ __launch_bounds__(256) void lstm_step(const short* __restrict__ gx,   // [S][64][4096]
                                                 const short* __restrict__ wh,   // [4096][1024]
                                                 const short* __restrict__ h_in, // [64][1024]
                                                 short* __restrict__ h_out,
                                                 float* __restrict__ c,          // [64][1024]
                                                 float* __restrict__ out,        // outputs base
                                                 int t) {
  __shared__ __align__(16) short As[2][4096];  // h tile  [64][64] bf16, 128-B rows (swizzled)
  __shared__ __align__(16) short Bs[2][2048];  // W tile  [32][64]
  __shared__ float pre[64][33];

  const int tid = threadIdx.x, wave = tid >> 6, lane = tid & 63;
  const int r0 = blockIdx.x * 32;

  const char* hinB = (const char*)h_in;
  const char* whB  = (const char*)(wh + (size_t)r0 * NH);

  f32x4 acc0 = {}, acc1 = {};

  // stage with XOR-swizzled SOURCE (LDS dest linear; read applies same XOR) — rule #21
  auto stage = [&](int kt, int buf) {
#pragma unroll
    for (int s2 = 0; s2 < 2; ++s2) {
      int seg = wave * 2 + s2;
      int L   = seg * 1024 + lane * 16;
      int row = L >> 7;           // 128-B rows
      int cb  = L & 127;
      int scb = cb ^ ((row & 7) << 4);
      gload16(hinB + (size_t)row * 2048 + kt * 128 + scb, (char*)&As[buf][0] + L);
    }
    {
      int L   = wave * 1024 + lane * 16;
      int row = L >> 7;
      int cb  = L & 127;
      int scb = cb ^ ((row & 7) << 4);
      gload16(whB + (size_t)row * 2048 + kt * 128 + scb, (char*)&Bs[buf][0] + L);
    }
  };

  auto compute = [&](int buf) {
    const char* Ab = (const char*)&As[buf][0];
    const char* Bb = (const char*)&Bs[buf][0];
    const int arow = wave * 16 + (lane & 15);
    const int b0r  = lane & 15, b1r = 16 + (lane & 15);
#pragma unroll
    for (int ks = 0; ks < 2; ++ks) {
      int cb = ks * 64 + (lane >> 4) * 16;
      bf16x8 a  = *(const bf16x8*)(Ab + arow * 128 + (cb ^ ((arow & 7) << 4)));
      bf16x8 b0 = *(const bf16x8*)(Bb + b0r * 128 + (cb ^ ((b0r & 7) << 4)));
      bf16x8 b1 = *(const bf16x8*)(Bb + b1r * 128 + (cb ^ ((b1r & 7) << 4)));
      acc0 = __builtin_amdgcn_mfma_f32_16x16x32_bf16(a, b0, acc0, 0, 0, 0);
      acc1 = __builtin_amdgcn_mfma_f32_16x16x32_bf16(a, b1, acc1, 0, 0, 0);
    }
  };

  stage(0, 0);
  __syncthreads();
  int buf = 0;
  for (int kt = 0; kt < 16; ++kt) {
    if (kt < 15) stage(kt + 1, buf ^ 1);
    compute(buf);
    __syncthreads();
    buf ^= 1;
  }

  // epilogue: add gx, park pre-activations in LDS
  {
    const int    col0 = lane & 15;
    const int    mB   = wave * 16 + (lane >> 4) * 4;
    const short* gxs  = gx + (size_t)t * NB * NR;
#pragma unroll
    for (int q = 0; q < 4; ++q) {
      int m = mB + q;
      pre[m][col0]      = acc0[q] + bf2f(gxs[(size_t)m * NR + r0 + col0]);
      pre[m][col0 + 16] = acc1[q] + bf2f(gxs[(size_t)m * NR + r0 + col0 + 16]);
    }
  }
  __syncthreads();

  // pointwise: 512 (b, j) items; jj-fast mapping for coalesced-ish stores
  const int j0 = blockIdx.x * 8;
#pragma unroll
  for (int it = 0; it < 2; ++it) {
    int item = tid * 2 + it;
    int jj = item & 7, b = item >> 3;
    float vi = pre[b][jj * 4 + 0];
    float vf = pre[b][jj * 4 + 1];
    float vg = pre[b][jj * 4 + 2];
    float vo = pre[b][jj * 4 + 3];
    float ig = sigm(vi), fg = sigm(vf), gg = tanhf(vg), og = sigm(vo);
    int   ci = b * NH + j0 + jj;
    float cn = fg * c[ci] + ig * gg;
    float hn = og * tanhf(cn);
    c[ci]     = cn;
    h_out[ci] = f2bf(hn);
    out[((size_t)t * NB + b) * NH + j0 + jj] = hn;
    if (t == S_LEN - 1) {
      float* oh = out + (size_t)S_LEN * NB * NH;
      oh[ci]           = hn;   // final h
      oh[NB * NH + ci] = cn;   // final c
    }
  }
}

// ---------------- launch ----------------

extern "C" void kernel_launch(void* const* d_in, const int* in_sizes, int n_in,
                              void* d_out, int out_size, void* d_ws, size_t ws_size,
                              hipStream_t stream) {
  const float* x   = (const float*)d_in[0];
  const float* wxi = (const float*)d_in[1];
  const float* bxi = (const float*)d_in[2];
  const float* whi = (const float*)d_in[3];
  const float* bhi = (const float*)d_in[4];
  const float* bi  = (const float*)d_in[5];
  const float* wxf = (const float*)d_in[6];
  const float* bxf = (const float*)d_in[7];
  const float* whf = (const float*)d_in[8];
  const float* bhf = (const float*)d_in[9];
  const float* bf  = (const float*)d_in[10];
  const float* wxc = (const float*)d_in[11];
  const float* bxc = (const float*)d_in[12];
  const float* whc = (const float*)d_in[13];
  const float* bhc = (const float*)d_in[14];
  const float* bc  = (const float*)d_in[15];
  const float* wxo = (const float*)d_in[16];
  const float* bxo = (const float*)d_in[17];
  const float* who = (const float*)d_in[18];
  const float* bho = (const float*)d_in[19];
  const float* bo  = (const float*)d_in[20];

  char* ws = (char*)d_ws;
  const size_t SB = (size_t)S_LEN * NB;
  size_t off = 0;
  short* gx    = (short*)(ws + off); off += SB * NR * 2;        // 268 MB
  short* xbf   = (short*)(ws + off); off += SB * NI * 2;        // 67 MB
  short* wxcat = (short*)(ws + off); off += (size_t)NR * NI * 2;
  short* whcat = (short*)(ws + off); off += (size_t)NR * NH * 2;
  float* bias  = (float*)(ws + off); off += NR * 4;
  short* h0    = (short*)(ws + off); off += NB * NH * 2;
  short* h1    = (short*)(ws + off); off += NB * NH * 2;
  float* cbuf  = (float*)(ws + off); off += NB * NH * 4;
  (void)ws_size; (void)in_sizes; (void)n_in; (void)out_size;

  float* out = (float*)d_out;

  k_convert_x<<<(int)(SB * NI / 4 / 256), 256, 0, stream>>>(x, xbf);
  WPtrs wp = {wxi, wxf, wxc, wxo, whi, whf, whc, who};
  k_pack_w<<<(NR * NI / 4) / 256, 256, 0, stream>>>(wp, wxcat, whcat);
  BPtrs bp = {bxi, bhi, bi, bxf, bhf, bf, bxc, bhc, bc, bxo, bho, bo};
  k_init<<<(NB * NH) / 256, 256, 0, stream>>>(bp, bias, h0, h1, cbuf);

  gemm_x<<<dim3(SB / 128, NR / 128), 256, 0, stream>>>(xbf, wxcat, bias, gx);

  for (int t = 0; t < S_LEN; ++t) {
    const short* hin  = (t & 1) ? h1 : h0;
    short*       hout = (t & 1) ? h0 : h1;
    lstm_step<<<128, 256, 0, stream>>>(gx, whcat, hin, hout, cbuf, out, t);
  }
}